// Round 8
// baseline (180.685 us; speedup 1.0000x reference)
//
#include <hip/hip_runtime.h>
#include <hip/hip_bf16.h>

#define BB 4
#define SEQ 2048
#define NH 4
#define D 64
#define NPAIR 16
#define HOUT 8
#define LOSS_BASE ((size_t)BB * SEQ * HOUT * D)

// ---- float ws layout ----
#define OFF_PART 0                              // part[8][16][3][4096]
#define N_PART   (8 * 16 * 3 * 4096)
#define OFF_SPART (OFF_PART + N_PART)           // Spart[16][32][64]
#define N_SPART  (16 * 32 * 64)
#define OFF_LPART (OFF_SPART + N_SPART)         // lpart[2][16][4][2048]
#define N_LPART  (2 * 16 * 4 * 2048)
#define OFF_OPART (OFF_LPART + N_LPART)         // Opart[2][16][2048][64]
#define N_OPART  (2 * 16 * 2048 * 64)
#define OFF_US   (OFF_OPART + N_OPART)
// ushort arrays, each 16*2048*64: Khi, VbfT, UhT, EhiT, EloT, valsT
#define USZ ((size_t)16 * 2048 * 64)

typedef __attribute__((ext_vector_type(8))) short bf16x8;
typedef __attribute__((ext_vector_type(4))) float f32x4;
typedef __attribute__((ext_vector_type(8))) unsigned short us8;
typedef __attribute__((ext_vector_type(4))) unsigned short us4;

__device__ __forceinline__ unsigned short f2bf(float x) {
    union { float f; unsigned u; } v; v.f = x;
    unsigned r = v.u + 0x7fffu + ((v.u >> 16) & 1u);
    return (unsigned short)(r >> 16);
}
__device__ __forceinline__ float bf2f(unsigned short u) {
    union { unsigned u; float f; } v; v.u = ((unsigned)u) << 16; return v.f;
}
__device__ __forceinline__ void load16(const float* p, float* v) {
    const float4* q = (const float4*)p;
    float4 a = q[0], b = q[1], c = q[2], d = q[3];
    v[0]=a.x; v[1]=a.y; v[2]=a.z; v[3]=a.w;
    v[4]=b.x; v[5]=b.y; v[6]=b.z; v[7]=b.w;
    v[8]=c.x; v[9]=c.y; v[10]=c.z; v[11]=c.w;
    v[12]=d.x; v[13]=d.y; v[14]=d.z; v[15]=d.w;
}
__device__ __forceinline__ void wr_bf16x16(unsigned short* dst, const float* v) {
    us8 w0, w1;
#pragma unroll
    for (int i = 0; i < 8; i++) { w0[i] = f2bf(v[i]); w1[i] = f2bf(v[8 + i]); }
    *(us8*)dst = w0; *(us8*)(dst + 8) = w1;
}

// ================= prep: conversions / transposes (unchanged from R7) =================
__global__ __launch_bounds__(256) void prep(const float* __restrict__ U, const float* __restrict__ Vagf,
                                            const float* __restrict__ vals, const float* __restrict__ Ksm,
                                            const float* __restrict__ Vsm,
                                            float* __restrict__ ws, unsigned short* __restrict__ usb,
                                            float* __restrict__ out) {
    int lt = blockIdx.x, p = blockIdx.y;
    int b = p >> 2, h = p & 3;
    int tid = threadIdx.x;
    int r = tid >> 2;
    int c4 = tid & 3;
    int c0 = c4 * 16;
    __shared__ float T[64][68];
    unsigned short* Khi   = usb;
    unsigned short* VbfT  = usb + USZ;
    unsigned short* UhT   = usb + 2 * USZ;
    unsigned short* EhiT  = usb + 3 * USZ;
    unsigned short* EloT  = usb + 4 * USZ;
    unsigned short* valsT = usb + 5 * USZ;
    float* Spart = ws + OFF_SPART;

    const size_t gbase = ((size_t)(b * SEQ + lt * 64 + r) * NH + h) * D + c0;
    const size_t tbase = ((size_t)p * 64 + r) * 2048 + lt * 64 + c0;
    float v[16], e[16];

    // 1: U -> row softmax -> UhT
    load16(U + gbase, v);
    float mx = v[0];
#pragma unroll
    for (int k = 1; k < 16; k++) mx = fmaxf(mx, v[k]);
    mx = fmaxf(mx, __shfl_xor(mx, 1));
    mx = fmaxf(mx, __shfl_xor(mx, 2));
    float sm = 0.0f;
#pragma unroll
    for (int k = 0; k < 16; k++) { v[k] = __expf(v[k] - mx); sm += v[k]; }
    sm += __shfl_xor(sm, 1);
    sm += __shfl_xor(sm, 2);
    float inv = 1.0f / sm;
#pragma unroll
    for (int k = 0; k < 16; k++) T[r][c0 + k] = v[k] * inv;
    __syncthreads();
#pragma unroll
    for (int k = 0; k < 16; k++) e[k] = T[c0 + k][r];
    wr_bf16x16(UhT + tbase, e);
    __syncthreads();

    // 2: E = exp(Vagf) -> EhiT/EloT + col sums
    load16(Vagf + gbase, v);
#pragma unroll
    for (int k = 0; k < 16; k++) T[r][c0 + k] = __expf(v[k]);
    __syncthreads();
    float ssum = 0.0f;
#pragma unroll
    for (int k = 0; k < 16; k++) { e[k] = T[c0 + k][r]; ssum += e[k]; }
    ssum += __shfl_xor(ssum, 1);
    ssum += __shfl_xor(ssum, 2);
    if (c4 == 0) Spart[(p * 32 + lt) * 64 + r] = ssum;
    {
        us8 h0, h1, l0, l1;
#pragma unroll
        for (int i = 0; i < 8; i++) {
            unsigned short hh = f2bf(e[i]);
            h0[i] = hh; l0[i] = f2bf(e[i] - bf2f(hh));
            unsigned short h2 = f2bf(e[8 + i]);
            h1[i] = h2; l1[i] = f2bf(e[8 + i] - bf2f(h2));
        }
        *(us8*)(EhiT + tbase) = h0; *(us8*)(EhiT + tbase + 8) = h1;
        *(us8*)(EloT + tbase) = l0; *(us8*)(EloT + tbase + 8) = l1;
    }
    __syncthreads();

    // 3: vals -> valsT
    load16(vals + gbase, v);
#pragma unroll
    for (int k = 0; k < 16; k++) T[r][c0 + k] = v[k];
    __syncthreads();
#pragma unroll
    for (int k = 0; k < 16; k++) e[k] = T[c0 + k][r];
    wr_bf16x16(valsT + tbase, e);
    __syncthreads();

    // 4: Vsm -> VbfT
    load16(Vsm + gbase, v);
#pragma unroll
    for (int k = 0; k < 16; k++) T[r][c0 + k] = v[k];
    __syncthreads();
#pragma unroll
    for (int k = 0; k < 16; k++) e[k] = T[c0 + k][r];
    wr_bf16x16(VbfT + tbase, e);

    // 5: K -> Khi (row-major)
    load16(Ksm + gbase, v);
    wr_bf16x16(Khi + ((size_t)(p * SEQ + lt * 64 + r)) * 64 + c0, v);

    if (lt == 0 && p == 0 && tid < BB) out[LOSS_BASE + tid] = 0.0f;
}

// ================= mid: flash5 (blocks 0..1023) + gram split-8 (1024..1151) =================
#define PSTR 72
#define FIXM 10.0f

__global__ __launch_bounds__(256, 3) void mid(const unsigned short* __restrict__ usb,
                                              const float* __restrict__ Q,
                                              float* __restrict__ part,
                                              float* __restrict__ Opart, float* __restrict__ lpart) {
    __shared__ __align__(16) unsigned char smem[20480];
    const int bid = blockIdx.x;
    const int tid = threadIdx.x;
    const int w = tid >> 6, lane = tid & 63, lm = lane & 15, quad = lane >> 4;

    if (bid < 1024) {
        // ---------------- flash5: wave-specialized keys/d, K/V direct from global ----------------
        int qt = bid & 31, p = (bid >> 5) & 15, half = bid >> 9;
        int b = p >> 2, h = p & 3;
        const unsigned short* Khi  = usb;
        const unsigned short* VbfT = usb + USZ;
        unsigned short* Ph = (unsigned short*)smem;    // [64 qrow][PSTR]

        // Q B-frags for all 4 n-tiles: B[n=lm][k=quad*8+j], d = ks*32+quad*8+j, scale 1/8
        bf16x8 qhi[4][2], qlo[4][2];
#pragma unroll
        for (int nq = 0; nq < 4; nq++) {
            const float* qp = Q + ((size_t)(b * SEQ + qt * 64 + nq * 16 + lm) * NH + h) * D + quad * 8;
#pragma unroll
            for (int ks = 0; ks < 2; ks++) {
                float4 a0 = *(const float4*)(qp + ks * 32);
                float4 a1 = *(const float4*)(qp + ks * 32 + 4);
                float qq[8] = {a0.x, a0.y, a0.z, a0.w, a1.x, a1.y, a1.z, a1.w};
#pragma unroll
                for (int j = 0; j < 8; j++) {
                    float xs = qq[j] * 0.125f;
                    unsigned short hi = f2bf(xs);
                    qhi[nq][ks][j] = (short)hi;
                    qlo[nq][ks][j] = (short)f2bf(xs - bf2f(hi));
                }
            }
        }

        float rsum[4] = {0.f, 0.f, 0.f, 0.f};
        f32x4 o[4];
#pragma unroll
        for (int t = 0; t < 4; t++) o[t] = (f32x4){0.f, 0.f, 0.f, 0.f};

        // A-frag global addresses:
        // K[key=kt*64+w*16+lm][d=ks*32+quad*8..] ; V^T[d=w*16+lm][key=kt*64+ks*32+quad*8..]
        const size_t kbase = ((size_t)p * SEQ + (size_t)half * 1024 + w * 16 + lm) * 64 + quad * 8;
        const size_t vbase = ((size_t)p * 64 + w * 16 + lm) * 2048 + (size_t)half * 1024 + quad * 8;
        bf16x8 kf[2], vf[2], kf2[2], vf2[2];
#pragma unroll
        for (int ks = 0; ks < 2; ks++) {
            kf[ks] = *(const bf16x8*)(Khi + kbase + ks * 32);
            vf[ks] = *(const bf16x8*)(VbfT + vbase + ks * 32);
        }

        for (int it = 0; it < 16; ++it) {
            // ---- S^T tile: m=key(w's 16), n=qrow(nq*16+lm): A=K, B=Q (2-pass hi/lo) ----
            f32x4 s[4];
#pragma unroll
            for (int t = 0; t < 4; t++) s[t] = (f32x4){0.f, 0.f, 0.f, 0.f};
#pragma unroll
            for (int ks = 0; ks < 2; ks++)
#pragma unroll
                for (int nq = 0; nq < 4; nq++) {
                    s[nq] = __builtin_amdgcn_mfma_f32_16x16x32_bf16(kf[ks], qhi[nq][ks], s[nq], 0, 0, 0);
                    s[nq] = __builtin_amdgcn_mfma_f32_16x16x32_bf16(kf[ks], qlo[nq][ks], s[nq], 0, 0, 0);
                }
            // prefetch next K/V frags (overlaps exp + PV)
            if (it < 15) {
#pragma unroll
                for (int ks = 0; ks < 2; ks++) {
                    kf2[ks] = *(const bf16x8*)(Khi + kbase + (it + 1) * 64ull * 64 + ks * 32);
                    vf2[ks] = *(const bf16x8*)(VbfT + vbase + (it + 1) * 64 + ks * 32);
                }
            }
            // ---- exp(s - FIXM), pack, write Ph[qrow][key] ----
#pragma unroll
            for (int nq = 0; nq < 4; nq++) {
                us4 pk;
#pragma unroll
                for (int r = 0; r < 4; r++) {
                    float e = __expf(s[nq][r] - FIXM);
                    rsum[nq] += e;
                    pk[r] = f2bf(e);
                }
                *(us4*)&Ph[(nq * 16 + lm) * PSTR + w * 16 + quad * 4] = pk;
            }
            __syncthreads();    // P complete (cross-wave)

            // ---- O^T += V^T · P^T : A=V^T (w's 16 d), B=P ----
#pragma unroll
            for (int ks = 0; ks < 2; ks++)
#pragma unroll
                for (int nq = 0; nq < 4; nq++) {
                    bf16x8 pf = *(const bf16x8*)&Ph[(nq * 16 + lm) * PSTR + ks * 32 + quad * 8];
                    o[nq] = __builtin_amdgcn_mfma_f32_16x16x32_bf16(vf[ks], pf, o[nq], 0, 0, 0);
                }
            __syncthreads();    // PV reads done before next Ph overwrite
#pragma unroll
            for (int ks = 0; ks < 2; ks++) { kf[ks] = kf2[ks]; vf[ks] = vf2[ks]; }
        }

        // ---- epilogue ----
#pragma unroll
        for (int nq = 0; nq < 4; nq++) {
            float rs = rsum[nq];
            rs += __shfl_xor(rs, 16);
            rs += __shfl_xor(rs, 32);       // sum over quad -> wave-partial for qrow nq*16+lm
            int row = qt * 64 + nq * 16 + lm;
            // O^T: lane holds d = w*16+quad*4+reg at qrow=row
            *(f32x4*)(Opart + ((size_t)(half * 16 + p) * SEQ + row) * 64 + w * 16 + quad * 4) = o[nq];
            if (quad == 0)
                lpart[((size_t)(half * 16 + p) * 4 + w) * SEQ + row] = rs;
        }
    } else {
        // ---------------- gram: MFMA split-8 partials ----------------
        int j = bid - 1024;
        int split = j >> 4, p = j & 15;
        const unsigned short* UhT   = usb + 2 * USZ;
        const unsigned short* EhiT  = usb + 3 * USZ;
        const unsigned short* EloT  = usb + 4 * USZ;
        const unsigned short* valsT = usb + 5 * USZ;
        unsigned short* Ut = (unsigned short*)smem;            // 64*40
        unsigned short* Eh = Ut + 64 * 40;
        unsigned short* El = Eh + 64 * 40;
        unsigned short* Vt = El + 64 * 40;
        f32x4 su[4], sv[4], kv[4];
#pragma unroll
        for (int i = 0; i < 4; i++) { su[i] = (f32x4){0,0,0,0}; sv[i] = (f32x4){0,0,0,0}; kv[i] = (f32x4){0,0,0,0}; }
        int srow = tid >> 2;
        int sseg = (tid & 3) * 8;

        for (int step = 0; step < 8; ++step) {
            int l0 = split * 256 + step * 32;
            __syncthreads();
            size_t gb = ((size_t)p * 64 + srow) * 2048 + l0 + sseg;
            *(us8*)&Ut[srow * 40 + sseg] = *(const us8*)(UhT + gb);
            *(us8*)&Eh[srow * 40 + sseg] = *(const us8*)(EhiT + gb);
            *(us8*)&El[srow * 40 + sseg] = *(const us8*)(EloT + gb);
            *(us8*)&Vt[srow * 40 + sseg] = *(const us8*)(valsT + gb);
            __syncthreads();
            int ao = (w * 16 + lm) * 40 + quad * 8;
            bf16x8 au  = *(const bf16x8*)&Ut[ao];
            bf16x8 aeh = *(const bf16x8*)&Eh[ao];
            bf16x8 ael = *(const bf16x8*)&El[ao];
#pragma unroll
            for (int nt = 0; nt < 4; nt++) {
                int bo = (nt * 16 + lm) * 40 + quad * 8;
                bf16x8 bu  = *(const bf16x8*)&Ut[bo];
                bf16x8 beh = *(const bf16x8*)&Eh[bo];
                bf16x8 bv  = *(const bf16x8*)&Vt[bo];
                su[nt] = __builtin_amdgcn_mfma_f32_16x16x32_bf16(au,  bu,  su[nt], 0, 0, 0);
                sv[nt] = __builtin_amdgcn_mfma_f32_16x16x32_bf16(aeh, beh, sv[nt], 0, 0, 0);
                kv[nt] = __builtin_amdgcn_mfma_f32_16x16x32_bf16(aeh, bv,  kv[nt], 0, 0, 0);
                kv[nt] = __builtin_amdgcn_mfma_f32_16x16x32_bf16(ael, bv,  kv[nt], 0, 0, 0);
            }
        }
        float* dst = part + (size_t)(split * 16 + p) * 3 * 4096;
#pragma unroll
        for (int nt = 0; nt < 4; nt++)
#pragma unroll
            for (int reg = 0; reg < 4; reg++) {
                int off = (w * 16 + quad * 4 + reg) * 64 + nt * 16 + lm;
                dst[off] = su[nt][reg];
                dst[4096 + off] = sv[nt][reg];
                dst[8192 + off] = kv[nt][reg];
            }
    }
}

// ================= post: smerge (0..2047) + agf_out/ortho (2048..2575) =================
__global__ __launch_bounds__(256) void post(const float* __restrict__ U, const float* __restrict__ Sg,
                                            const float* __restrict__ gam, const float* __restrict__ part,
                                            const float* __restrict__ Spart, const float* __restrict__ Opart,
                                            const float* __restrict__ lpart, float* __restrict__ out) {
    const int bid = blockIdx.x;
    const int tid = threadIdx.x;
    if (bid < 2048) {
        int idx = bid * 256 + tid;            // [p][l][16 dq]
        int p = idx >> 15;
        int rem = idx & 32767;
        int l = rem >> 4, dq = rem & 15;
        int b = p >> 2, h = p & 3;
        f32x4 a = *(const f32x4*)(Opart + ((size_t)p * SEQ + l) * 64 + dq * 4);
        f32x4 c = *(const f32x4*)(Opart + ((size_t)(16 + p) * SEQ + l) * 64 + dq * 4);
        float den = 0.0f;
#pragma unroll
        for (int hf = 0; hf < 2; hf++)
#pragma unroll
            for (int wv = 0; wv < 4; wv++)
                den += lpart[((size_t)(hf * 16 + p) * 4 + wv) * SEQ + l];
        *(f32x4*)(out + ((size_t)(b * SEQ + l) * HOUT + 4 + h) * D + dq * 4) = (a + c) * (1.0f / den);
        return;
    }
    int j = bid - 2048;
    int p = j / 33, lt = j % 33;
    __shared__ float cis[64];
    __shared__ float red[4][64];
    {
        int d = tid & 63, grp = tid >> 6;
        float s = 0.0f;
#pragma unroll
        for (int i = 0; i < 8; i++) s += Spart[(p * 32 + grp * 8 + i) * 64 + d];
        red[grp][d] = s;
        __syncthreads();
        if (tid < 64) cis[tid] = 1.0f / (red[0][tid] + red[1][tid] + red[2][tid] + red[3][tid]);
        __syncthreads();
    }
    if (lt == 32) {
        float s = 0.0f;
        for (int idx = tid; idx < 8192; idx += 256) {
            int g = idx >> 12, i = idx & 4095;
            float v = 0.0f;
#pragma unroll
            for (int sp = 0; sp < 8; sp++) v += part[((size_t)(sp * 16 + p) * 3 + g) * 4096 + i];
            if (g) v *= cis[i >> 6] * cis[i & 63];
            float dg = ((i >> 6) == (i & 63)) ? 1.0f : 0.0f;
            s += fabsf(v - dg);
        }
#pragma unroll
        for (int o = 32; o > 0; o >>= 1) s += __shfl_xor(s, o);
        __shared__ float r4[4];
        if ((tid & 63) == 0) r4[tid >> 6] = s;
        __syncthreads();
        if (tid == 0) atomicAdd(&out[LOSS_BASE + (p >> 2)], (r4[0] + r4[1] + r4[2] + r4[3]) * (1.0f / 16384.0f));
        return;
    }
    int b = p >> 2, h = p & 3;
    __shared__ __align__(16) float kvs[64][68];
    __shared__ __align__(16) float ugs[64][68];
    for (int idx = tid; idx < 4096; idx += 256) {
        float v = 0.0f;
#pragma unroll
        for (int sp = 0; sp < 8; sp++) v += part[((size_t)(sp * 16 + p) * 3 + 2) * 4096 + idx];
        kvs[idx >> 6][idx & 63] = v * cis[idx >> 6];
    }
    {
        int row = tid >> 2;
        int c16 = (tid & 3) * 16;
        size_t ibase = ((size_t)((b * SEQ + lt * 64 + row) * NH + h)) * D + c16;
        float uv[16];
        load16(U + ibase, uv);
        float mx = uv[0];
#pragma unroll
        for (int k = 1; k < 16; k++) mx = fmaxf(mx, uv[k]);
        mx = fmaxf(mx, __shfl_xor(mx, 1));
        mx = fmaxf(mx, __shfl_xor(mx, 2));
        float sm = 0.0f;
#pragma unroll
        for (int k = 0; k < 16; k++) { uv[k] = __expf(uv[k] - mx); sm += uv[k]; }
        sm += __shfl_xor(sm, 1);
        sm += __shfl_xor(sm, 2);
        float inv = 1.0f / sm;
        float sg[16];
        load16(Sg + ibase, sg);
        float g0 = gam[0], g1 = gam[1], g2 = gam[2], g3 = gam[3];
#pragma unroll
        for (int k = 0; k < 16; k++) {
            float sig = 1.0f / (1.0f + __expf(-sg[k]));
            float x1 = 2.0f * sig;
            float x2 = 1.875f * sig * x1 - 0.75f;
            float x3 = 1.8666666666666667f * sig * x2 - 0.8f * x1;
            float gf = g0 + g1 * x1 + g2 * x2 + g3 * x3;
            ugs[row][c16 + k] = uv[k] * inv * gf;
        }
    }
    __syncthreads();
    int tx = tid & 15, ty = tid >> 4;
    float acc[4][4] = {};
#pragma unroll 8
    for (int x = 0; x < 64; x++) {
        float4 kt = *(const float4*)&kvs[x][tx * 4];
        float kb[4] = {kt.x, kt.y, kt.z, kt.w};
#pragma unroll
        for (int a = 0; a < 4; a++) {
            float ua = ugs[ty * 4 + a][x];
#pragma unroll
            for (int e2 = 0; e2 < 4; e2++) acc[a][e2] = fmaf(ua, kb[e2], acc[a][e2]);
        }
    }
#pragma unroll
    for (int a = 0; a < 4; a++)
#pragma unroll
        for (int e2 = 0; e2 < 4; e2++)
            out[((size_t)(b * SEQ + lt * 64 + ty * 4 + a) * HOUT + h) * D + tx * 4 + e2] = acc[a][e2];
}

extern "C" void kernel_launch(void* const* d_in, const int* in_sizes, int n_in,
                              void* d_out, int out_size, void* d_ws, size_t ws_size,
                              hipStream_t stream) {
    (void)in_sizes; (void)n_in; (void)out_size; (void)ws_size;
    const float* U    = (const float*)d_in[0];
    const float* Sg   = (const float*)d_in[1];
    const float* V    = (const float*)d_in[2];
    const float* vals = (const float*)d_in[3];
    const float* Qs   = (const float*)d_in[4];
    const float* Ks   = (const float*)d_in[5];
    const float* Vv   = (const float*)d_in[6];
    const float* gam  = (const float*)d_in[7];
    float* out = (float*)d_out;

    float* ws = (float*)d_ws;
    float* part  = ws + OFF_PART;
    float* Spart = ws + OFF_SPART;
    float* lpart = ws + OFF_LPART;
    float* Opart = ws + OFF_OPART;
    unsigned short* usb = (unsigned short*)(ws + OFF_US);

    prep<<<dim3(32, 16), 256, 0, stream>>>(U, V, vals, Ks, Vv, ws, usb, out);
    mid<<<1152, 256, 0, stream>>>(usb, Qs, part, Opart, lpart);
    post<<<2576, 256, 0, stream>>>(U, Sg, gam, part, Spart, Opart, lpart, out);
}